// Round 8
// baseline (2351.155 us; speedup 1.0000x reference)
//
#include <hip/hip_runtime.h>

#define B_ 64
#define T_ 512
#define E_ 512
#define HD_ 256
#define H_ 512
#define K_ 16
#define NEG_ (-10000.0f)
#define START_ 13
#define STOP_ 14

typedef unsigned int u32;
using half8  = __attribute__((ext_vector_type(8))) _Float16;
using f32x4  = __attribute__((ext_vector_type(4))) float;
using half2v = __attribute__((ext_vector_type(2))) _Float16;

__device__ __forceinline__ int dot4i8(u32 a, u32 b, int c) {
#if __has_builtin(__builtin_amdgcn_sdot4)
    return __builtin_amdgcn_sdot4((int)a, (int)b, c, false);
#else
    int r = c;
#pragma unroll
    for (int i = 0; i < 4; ++i) {
        int xa = ((int)a << (24 - 8 * i)) >> 24;
        int xb = ((int)b << (24 - 8 * i)) >> 24;
        r += xa * xb;
    }
    return r;
#endif
}
__device__ __forceinline__ int dotq(uint4 w, uint4 h, int a) {
    a = dot4i8(w.x, h.x, a); a = dot4i8(w.y, h.y, a);
    a = dot4i8(w.z, h.z, a); a = dot4i8(w.w, h.w, a);
    return a;
}
__device__ __forceinline__ float sigm(float x) { return 1.f / (1.f + __expf(-x)); }
__device__ __forceinline__ float tanh_f(float x) {
    float a = fabsf(x);
    float e = __expf(-2.f * a);
    float t = (1.f - e) / (1.f + e);
    return x < 0.f ? -t : t;
}

// ---------------- converters ----------------
__global__ void cvt_f16_k(const float* __restrict__ src, _Float16* __restrict__ dst, int n4) {
    int i = blockIdx.x * blockDim.x + threadIdx.x;
    if (i < n4) {
        float4 v = ((const float4*)src)[i];
        half2v a; a.x = (_Float16)v.x; a.y = (_Float16)v.y;
        half2v b; b.x = (_Float16)v.z; b.y = (_Float16)v.w;
        ((u32*)dst)[2 * i]     = __builtin_bit_cast(u32, a);
        ((u32*)dst)[2 * i + 1] = __builtin_bit_cast(u32, b);
    }
}
__global__ void bias_sum_k(const float* __restrict__ bih, const float* __restrict__ bhh,
                           float* __restrict__ bs) {
    int i = blockIdx.x * blockDim.x + threadIdx.x;
    if (i < 4096) bs[i] = bih[i] + bhh[i];
}

// ---------------- W_hh row-scaled int8 quantization: one 64-thread block per row ------
__global__ void quant_whh_k(const float* __restrict__ whh,   // [4096][256]
                            u32* __restrict__ wq,            // [4096][64] packed i8
                            float* __restrict__ dqw) {       // [4096] dequant = rowmax/127^2
    const int row = blockIdx.x, lane = threadIdx.x;          // 64 lanes
    const float4 v = ((const float4*)(whh + (size_t)row * 256))[lane];
    float m = fmaxf(fmaxf(fabsf(v.x), fabsf(v.y)), fmaxf(fabsf(v.z), fabsf(v.w)));
#pragma unroll
    for (int off = 32; off >= 1; off >>= 1) m = fmaxf(m, __shfl_xor(m, off, 64));
    m = fmaxf(m, 1e-8f);
    const float s = 127.f / m;
    int b0 = ((int)rintf(v.x * s)) & 255;
    int b1 = ((int)rintf(v.y * s)) & 255;
    int b2 = ((int)rintf(v.z * s)) & 255;
    int b3 = ((int)rintf(v.w * s)) & 255;
    wq[(size_t)row * 64 + lane] = (u32)(b0 | (b1 << 8) | (b2 << 16) | (b3 << 24));
    if (lane == 0) dqw[row] = m / (127.f * 127.f);
}

// ---------------- embedding gather + cast to f16 ----------------
__global__ void embed_k(const int* __restrict__ x, const float* __restrict__ emb,
                        _Float16* __restrict__ xe) {
    int m = blockIdx.x;                  // 0..32767 = b*T + t
    int row = x[m];
    int c = threadIdx.x * 4;             // 128 threads * 4 = 512
    float4 v = *(const float4*)(emb + (size_t)row * E_ + c);
    half2v p0; p0.x = (_Float16)v.x; p0.y = (_Float16)v.y;
    half2v p1; p1.x = (_Float16)v.z; p1.y = (_Float16)v.w;
    u32* dst = (u32*)(xe + (size_t)m * E_) + threadIdx.x * 2;
    dst[0] = __builtin_bit_cast(u32, p0);
    dst[1] = __builtin_bit_cast(u32, p1);
}

// ---------------- f16 MFMA GEMM:  C[m,n] = sum_k A[m,k]*Bw[n,k] + bias[n]  (C f16) -----
__global__ __launch_bounds__(256) void gemm_bt(const _Float16* __restrict__ A,
                                               const _Float16* __restrict__ Bw,
                                               const float* __restrict__ bsum,
                                               _Float16* __restrict__ C,
                                               int M, int N, int Kd) {
    __shared__ __align__(16) _Float16 As[128 * 64];
    __shared__ __align__(16) _Float16 Bs[128 * 64];
    const int nTn = N >> 7;
    const int tm = blockIdx.x / nTn, tn = blockIdx.x % nTn;
    const int tid = threadIdx.x;
    const int lane = tid & 63, wave = tid >> 6;
    const int wr = wave >> 1, wc = wave & 1;      // 2x2 waves of 64x64
    f32x4 acc[4][4];
#pragma unroll
    for (int i = 0; i < 4; ++i)
#pragma unroll
        for (int j = 0; j < 4; ++j) acc[i][j] = f32x4{0.f, 0.f, 0.f, 0.f};
    const int lr = lane & 15, lk = (lane >> 4) * 8;

    for (int k0 = 0; k0 < Kd; k0 += 64) {
#pragma unroll
        for (int r = 0; r < 4; ++r) {
            int c = r * 256 + tid;                     // chunk id, 16B each
            const _Float16* srcA = A + (size_t)(tm * 128 + (c >> 3)) * Kd + k0 + (c & 7) * 8;
            const _Float16* srcB = Bw + (size_t)(tn * 128 + (c >> 3)) * Kd + k0 + (c & 7) * 8;
            _Float16* dA = &As[(size_t)(r * 256 + wave * 64) * 8];
            _Float16* dB = &Bs[(size_t)(r * 256 + wave * 64) * 8];
            __builtin_amdgcn_global_load_lds((const __attribute__((address_space(1))) void*)srcA,
                                             (__attribute__((address_space(3))) void*)dA, 16, 0, 0);
            __builtin_amdgcn_global_load_lds((const __attribute__((address_space(1))) void*)srcB,
                                             (__attribute__((address_space(3))) void*)dB, 16, 0, 0);
        }
        __syncthreads();
#pragma unroll
        for (int kk = 0; kk < 2; ++kk) {
            half8 av[4], bv[4];
#pragma unroll
            for (int i = 0; i < 4; ++i)
                av[i] = *(const half8*)&As[(wr * 64 + i * 16 + lr) * 64 + kk * 32 + lk];
#pragma unroll
            for (int j = 0; j < 4; ++j)
                bv[j] = *(const half8*)&Bs[(wc * 64 + j * 16 + lr) * 64 + kk * 32 + lk];
#pragma unroll
            for (int i = 0; i < 4; ++i)
#pragma unroll
                for (int j = 0; j < 4; ++j)
                    acc[i][j] = __builtin_amdgcn_mfma_f32_16x16x32_f16(av[i], bv[j], acc[i][j], 0, 0, 0);
        }
        __syncthreads();
    }
    const int mq = (lane >> 4) * 4;
#pragma unroll
    for (int i = 0; i < 4; ++i)
#pragma unroll
        for (int j = 0; j < 4; ++j) {
            int m0 = tm * 128 + wr * 64 + i * 16 + mq;
            int n0 = tn * 128 + wc * 64 + j * 16 + lr;
            float bv = bsum[n0];
#pragma unroll
            for (int q = 0; q < 4; ++q)
                C[(size_t)(m0 + q) * N + n0] = (_Float16)(acc[i][j][q] + bv);
        }
}

// ---------------- LSTM recurrence: 256 threads, thread = unit, 4 full rows in VGPRs ---
// Block = (b, dir), 128 blocks of 256 threads (4 waves = 1 wave/SIMD -> HW VGPR ceiling
// 512; demand ~340). Thread u owns unit u's ALL FOUR gate rows {u, u+256, u+512, u+768}
// = 256 weight-u32 register-resident. Consequences (R7 analysis: LDS h-broadcast data
// replication was the 1536-cyc/step bottleneck; 512 threads x 256 B = 128 KB/step):
//   - h LDS traffic halves (256 threads x 256 B = 64 KB/step ~= 770 cyc)
//   - gate combine is THREAD-LOCAL: g_sh exchange deleted, ONE barrier/step
//   - z and dq loads stay fully coalesced; c/h state never leaves the thread
__global__ __attribute__((amdgpu_flat_work_group_size(256, 256), amdgpu_waves_per_eu(1, 1)))
void lstm_layer_k(
    const u32* __restrict__ wq,           // [2][1024][64] packed i8 (this layer)
    const float* __restrict__ dqw,        // [2][1024] rowmax/127^2 (this layer)
    const float* __restrict__ h0,         // [2][64][256]
    const float* __restrict__ c0,         // [2][64][256]
    const _Float16* __restrict__ Z,       // [32768][2048] f16 preacts (x@Wih + bias)
    _Float16* __restrict__ Hout) {        // [32768][512] f16
    __shared__ __align__(16) u32 hbuf[2][64];   // i8 h, 256 units, parity double-buffer
    __shared__ float m0sh;
    const int tid = threadIdx.x;                 // 0..255 = unit index
    const int b = blockIdx.x >> 1, dir = blockIdx.x & 1;

    // --- weights: 4 full rows (i,f,g,o of unit tid), register-resident ---
    const uint4* w4 = (const uint4*)(wq + (size_t)dir * 1024 * 64);
    uint4 w0[16], w1[16], w2[16], w3[16];
#pragma unroll
    for (int i = 0; i < 16; ++i) {
        w0[i] = w4[(size_t)(0 * 256 + tid) * 16 + i];
        w1[i] = w4[(size_t)(1 * 256 + tid) * 16 + i];
        w2[i] = w4[(size_t)(2 * 256 + tid) * 16 + i];
        w3[i] = w4[(size_t)(3 * 256 + tid) * 16 + i];
    }
    // keep-live (non-volatile: schedulable, but severs SSA link to the loads so they
    // cannot be sunk/rematerialized into the T-loop)
#pragma unroll
    for (int i = 0; i < 16; ++i) {
        asm("" : "+v"(w0[i].x), "+v"(w0[i].y), "+v"(w0[i].z), "+v"(w0[i].w));
        asm("" : "+v"(w1[i].x), "+v"(w1[i].y), "+v"(w1[i].z), "+v"(w1[i].w));
        asm("" : "+v"(w2[i].x), "+v"(w2[i].y), "+v"(w2[i].z), "+v"(w2[i].w));
        asm("" : "+v"(w3[i].x), "+v"(w3[i].y), "+v"(w3[i].z), "+v"(w3[i].w));
    }
    const float dq0 = dqw[dir * 1024 + 0 * 256 + tid];
    const float dq1 = dqw[dir * 1024 + 1 * 256 + tid];
    const float dq2 = dqw[dir * 1024 + 2 * 256 + tid];
    const float dq3 = dqw[dir * 1024 + 3 * 256 + tid];

    // --- state: c local; wave 0 quantizes h0 with dynamic scale (|h0| can exceed 1) ---
    float c = c0[(size_t)dir * B_ * HD_ + b * HD_ + tid];
    if (tid < 64) {
        float4 hv = ((const float4*)(h0 + (size_t)dir * B_ * HD_ + (size_t)b * HD_))[tid];
        float am = fmaxf(fmaxf(fabsf(hv.x), fabsf(hv.y)), fmaxf(fabsf(hv.z), fabsf(hv.w)));
#pragma unroll
        for (int off = 32; off >= 1; off >>= 1) am = fmaxf(am, __shfl_xor(am, off, 64));
        am = fmaxf(am, 1e-6f);
        float sc = 127.f / am;
        int q0 = ((int)rintf(hv.x * sc)) & 255, q1 = ((int)rintf(hv.y * sc)) & 255;
        int q2 = ((int)rintf(hv.z * sc)) & 255, q3 = ((int)rintf(hv.w * sc)) & 255;
        hbuf[0][tid] = (u32)(q0 | (q1 << 8) | (q2 << 16) | (q3 << 24));
        if (tid == 0) m0sh = am;
    }
    // --- z: 4 coalesced 2B loads per thread, prefetched one step ahead ---
    const _Float16* Zr = Z + (size_t)b * T_ * 2048 + dir * 1024;
    const int t0 = dir ? (T_ - 1) : 0;
    float z0 = (float)Zr[(size_t)t0 * 2048 + 0 * 256 + tid];
    float z1 = (float)Zr[(size_t)t0 * 2048 + 1 * 256 + tid];
    float z2 = (float)Zr[(size_t)t0 * 2048 + 2 * 256 + tid];
    float z3 = (float)Zr[(size_t)t0 * 2048 + 3 * 256 + tid];
    __syncthreads();
    const float m0v = m0sh;
    // step-0 dequant carries the h0 scale; reset to steady-state after s==0
    float dqa = dq0 * m0v, dqb = dq1 * m0v, dqc = dq2 * m0v, dqd = dq3 * m0v;

    for (int s = 0; s < T_; ++s) {
        const int t = dir ? (T_ - 1 - s) : s;
        float zn0 = 0.f, zn1 = 0.f, zn2 = 0.f, zn3 = 0.f;
        if (s + 1 < T_) {
            const int tn = dir ? (t - 1) : (t + 1);
            zn0 = (float)Zr[(size_t)tn * 2048 + 0 * 256 + tid];
            zn1 = (float)Zr[(size_t)tn * 2048 + 1 * 256 + tid];
            zn2 = (float)Zr[(size_t)tn * 2048 + 2 * 256 + tid];
            zn3 = (float)Zr[(size_t)tn * 2048 + 3 * 256 + tid];
        }
        // --- 4 full-row dots: 64 dotq (256 sdot4), 8 independent chains for ILP ---
        const uint4* hb = (const uint4*)&hbuf[s & 1][0];
        uint4 hv[16];
#pragma unroll
        for (int i = 0; i < 16; ++i) hv[i] = hb[i];
        int p0 = 0, p1 = 0, p2 = 0, p3 = 0, q0 = 0, q1 = 0, q2 = 0, q3 = 0;
#pragma unroll
        for (int i = 0; i < 16; i += 2) {
            p0 = dotq(w0[i], hv[i], p0); q0 = dotq(w0[i + 1], hv[i + 1], q0);
            p1 = dotq(w1[i], hv[i], p1); q1 = dotq(w1[i + 1], hv[i + 1], q1);
            p2 = dotq(w2[i], hv[i], p2); q2 = dotq(w2[i + 1], hv[i + 1], q2);
            p3 = dotq(w3[i], hv[i], p3); q3 = dotq(w3[i + 1], hv[i + 1], q3);
        }
        // --- gates fully local: dequant + z, nonlinearity, state update ---
        const float gi = (float)(p0 + q0) * dqa + z0;
        const float gf = (float)(p1 + q1) * dqb + z1;
        const float gg = (float)(p2 + q2) * dqc + z2;
        const float go = (float)(p3 + q3) * dqd + z3;
        c = sigm(gf) * c + sigm(gi) * tanh_f(gg);
        const float h = sigm(go) * tanh_f(c);
        Hout[(size_t)(b * T_ + t) * H_ + dir * HD_ + tid] = (_Float16)h;
        ((signed char*)&hbuf[(s + 1) & 1][0])[tid] = (signed char)(int)rintf(h * 127.f);
        if (s == 0) { dqa = dq0; dqb = dq1; dqc = dq2; dqd = dq3; }
        z0 = zn0; z1 = zn1; z2 = zn2; z3 = zn3;
        __syncthreads();                        // h(s+1) complete; single barrier/step
    }
}

// ---------------- tag scores: out[m,kk] = H[m,:] . w_out[kk,:] + b_out[kk] ----------------
__global__ __launch_bounds__(256) void tag_k(const _Float16* __restrict__ Hs,
                                             const float* __restrict__ wout,
                                             const float* __restrict__ bout,
                                             float* __restrict__ out) {
    const int tid = threadIdx.x;
    const int mi = tid >> 4, kk = tid & 15;
    const int m = blockIdx.x * 16 + mi;
    const uint4* hrow = (const uint4*)(Hs + (size_t)m * H_);
    const float4* wrow = (const float4*)(wout + (size_t)kk * H_);
    float acc = 0.f;
#pragma unroll 8
    for (int i = 0; i < 64; ++i) {
        uint4 hv = hrow[i];
        float4 w0 = wrow[2 * i], w1 = wrow[2 * i + 1];
        half2v p0 = __builtin_bit_cast(half2v, hv.x), p1 = __builtin_bit_cast(half2v, hv.y);
        half2v p2 = __builtin_bit_cast(half2v, hv.z), p3 = __builtin_bit_cast(half2v, hv.w);
        acc += (float)p0.x * w0.x + (float)p0.y * w0.y + (float)p1.x * w0.z + (float)p1.y * w0.w
             + (float)p2.x * w1.x + (float)p2.y * w1.y + (float)p3.x * w1.z + (float)p3.y * w1.w;
    }
    out[(size_t)m * K_ + kk] = acc + bout[kk];
}

// ---------------- CRF forward (faithful to reference's cross-batch sum) ----------------
__global__ __launch_bounds__(1024) void crf_k(const float* __restrict__ tag,
                                              const float* __restrict__ trans,
                                              float* __restrict__ out) {
    __shared__ float albuf[2][64][17];
    const int tid = threadIdx.x;
    const int kn = tid >> 6, b = tid & 63;   // wave = next-tag, lane = batch
    float trow[16];
#pragma unroll
    for (int kp = 0; kp < 16; ++kp) trow[kp] = trans[kn * 16 + kp];
    albuf[0][b][kn] = (kn == START_) ? 0.f : NEG_;
    __syncthreads();
    int cur = 0;
    for (int t = 0; t < T_; ++t) {
        const float feat = tag[(size_t)(b * T_ + t) * K_ + kn];
        float v[16];
        float m = -3.4e38f;
#pragma unroll
        for (int kp = 0; kp < 16; ++kp) {
            v[kp] = albuf[cur][b][kp] + trow[kp];
            m = fmaxf(m, v[kp]);
        }
        float sm = 0.f;
#pragma unroll
        for (int kp = 0; kp < 16; ++kp) sm += __expf(v[kp] - m);
#pragma unroll
        for (int off = 32; off >= 1; off >>= 1) sm += __shfl_xor(sm, off, 64);
        albuf[cur ^ 1][b][kn] = feat + m + __logf(sm);
        __syncthreads();
        cur ^= 1;
    }
    const float term = albuf[cur][b][kn] + trans[STOP_ * 16 + kn];
    albuf[cur ^ 1][b][kn] = term;
    __syncthreads();
    if (tid < 64) {   // all in wave 0
        float mb = -3.4e38f;
#pragma unroll
        for (int k2 = 0; k2 < 16; ++k2) mb = fmaxf(mb, albuf[cur ^ 1][tid][k2]);
        float p = 0.f;
#pragma unroll
        for (int k2 = 0; k2 < 16; ++k2) p += __expf(albuf[cur ^ 1][tid][k2] - mb);
#pragma unroll
        for (int off = 32; off >= 1; off >>= 1) p += __shfl_xor(p, off, 64);
        out[(size_t)B_ * T_ * K_ + tid] = mb + __logf(p);
    }
}

extern "C" void kernel_launch(void* const* d_in, const int* in_sizes, int n_in,
                              void* d_out, int out_size, void* d_ws, size_t ws_size,
                              hipStream_t stream) {
    const int*   x     = (const int*)d_in[0];
    const float* emb   = (const float*)d_in[2];
    const float* w_ih  = (const float*)d_in[3];
    const float* w_hh  = (const float*)d_in[4];
    const float* b_ih  = (const float*)d_in[5];
    const float* b_hh  = (const float*)d_in[6];
    const float* h0    = (const float*)d_in[7];
    const float* c0    = (const float*)d_in[8];
    const float* w_out = (const float*)d_in[9];
    const float* b_out = (const float*)d_in[10];
    const float* trans = (const float*)d_in[11];
    float* out = (float*)d_out;

    // workspace layout (≈199 MB)
    char* ws = (char*)d_ws;
    u32*      wq    = (u32*)ws;                                   // 1 MB   [L][2][1024][64] i8-packed
    float*    dqw   = (float*)(ws + ((size_t)1 << 20));           // 16 KB  [L][2][1024]
    _Float16* wih16 = (_Float16*)(ws + ((size_t)2 << 20));        // 4 MB   [L][2048][512]
    float*    bsum  = (float*)(ws + ((size_t)6 << 20));           // 16 KB  [L][2048]
    _Float16* xe    = (_Float16*)(ws + ((size_t)7 << 20));        // 32 MB  [32768][512] (reused as H1)
    _Float16* Zb    = (_Float16*)(ws + ((size_t)39 << 20));       // 128 MB [32768][2048]
    _Float16* H0b   = (_Float16*)(ws + ((size_t)167 << 20));      // 32 MB  [32768][512]
    if (ws_size < ((size_t)199 << 20)) return;

    quant_whh_k<<<4096, 64, 0, stream>>>(w_hh, wq, dqw);
    cvt_f16_k<<<2048, 256, 0, stream>>>(w_ih, wih16, 2097152 / 4);
    bias_sum_k<<<16, 256, 0, stream>>>(b_ih, b_hh, bsum);
    embed_k<<<B_ * T_, 128, 0, stream>>>(x, emb, xe);

    // layer 0
    gemm_bt<<<(32768 / 128) * (2048 / 128), 256, 0, stream>>>(xe, wih16, bsum, Zb, 32768, 2048, 512);
    lstm_layer_k<<<128, 256, 0, stream>>>(wq, dqw, h0, c0, Zb, H0b);
    // layer 1
    gemm_bt<<<(32768 / 128) * (2048 / 128), 256, 0, stream>>>(H0b, wih16 + (size_t)2048 * 512, bsum + 2048, Zb, 32768, 2048, 512);
    lstm_layer_k<<<128, 256, 0, stream>>>(wq + (size_t)2048 * 64, dqw + 2048,
                                          h0 + 2 * B_ * HD_, c0 + 2 * B_ * HD_, Zb, xe /*H1*/);
    // emissions + CRF
    tag_k<<<32768 / 16, 256, 0, stream>>>(xe, w_out, b_out, out);
    crf_k<<<1, 1024, 0, stream>>>(out, trans, out);
}

// Round 9
// 2265.879 us; speedup vs baseline: 1.0376x; 1.0376x over previous
//
#include <hip/hip_runtime.h>

#define B_ 64
#define T_ 512
#define E_ 512
#define HD_ 256
#define H_ 512
#define K_ 16
#define NEG_ (-10000.0f)
#define START_ 13
#define STOP_ 14

typedef unsigned int u32;
using half8  = __attribute__((ext_vector_type(8))) _Float16;
using f32x4  = __attribute__((ext_vector_type(4))) float;
using half2v = __attribute__((ext_vector_type(2))) _Float16;

__device__ __forceinline__ int dot4i8(u32 a, u32 b, int c) {
#if __has_builtin(__builtin_amdgcn_sdot4)
    return __builtin_amdgcn_sdot4((int)a, (int)b, c, false);
#else
    int r = c;
#pragma unroll
    for (int i = 0; i < 4; ++i) {
        int xa = ((int)a << (24 - 8 * i)) >> 24;
        int xb = ((int)b << (24 - 8 * i)) >> 24;
        r += xa * xb;
    }
    return r;
#endif
}
__device__ __forceinline__ int dotq(uint4 w, uint4 h, int a) {
    a = dot4i8(w.x, h.x, a); a = dot4i8(w.y, h.y, a);
    a = dot4i8(w.z, h.z, a); a = dot4i8(w.w, h.w, a);
    return a;
}
__device__ __forceinline__ float sigm(float x) { return 1.f / (1.f + __expf(-x)); }
__device__ __forceinline__ float tanh_f(float x) {
    float a = fabsf(x);
    float e = __expf(-2.f * a);
    float t = (1.f - e) / (1.f + e);
    return x < 0.f ? -t : t;
}

// ---------------- converters ----------------
__global__ void cvt_f16_k(const float* __restrict__ src, _Float16* __restrict__ dst, int n4) {
    int i = blockIdx.x * blockDim.x + threadIdx.x;
    if (i < n4) {
        float4 v = ((const float4*)src)[i];
        half2v a; a.x = (_Float16)v.x; a.y = (_Float16)v.y;
        half2v b; b.x = (_Float16)v.z; b.y = (_Float16)v.w;
        ((u32*)dst)[2 * i]     = __builtin_bit_cast(u32, a);
        ((u32*)dst)[2 * i + 1] = __builtin_bit_cast(u32, b);
    }
}
__global__ void bias_sum_k(const float* __restrict__ bih, const float* __restrict__ bhh,
                           float* __restrict__ bs) {
    int i = blockIdx.x * blockDim.x + threadIdx.x;
    if (i < 4096) bs[i] = bih[i] + bhh[i];
}

// ---------------- W_hh row-scaled int8 quantization: one 64-thread block per row ------
__global__ void quant_whh_k(const float* __restrict__ whh,   // [4096][256]
                            u32* __restrict__ wq,            // [4096][64] packed i8
                            float* __restrict__ dqw) {       // [4096] dequant = rowmax/127^2
    const int row = blockIdx.x, lane = threadIdx.x;          // 64 lanes
    const float4 v = ((const float4*)(whh + (size_t)row * 256))[lane];
    float m = fmaxf(fmaxf(fabsf(v.x), fabsf(v.y)), fmaxf(fabsf(v.z), fabsf(v.w)));
#pragma unroll
    for (int off = 32; off >= 1; off >>= 1) m = fmaxf(m, __shfl_xor(m, off, 64));
    m = fmaxf(m, 1e-8f);
    const float s = 127.f / m;
    int b0 = ((int)rintf(v.x * s)) & 255;
    int b1 = ((int)rintf(v.y * s)) & 255;
    int b2 = ((int)rintf(v.z * s)) & 255;
    int b3 = ((int)rintf(v.w * s)) & 255;
    wq[(size_t)row * 64 + lane] = (u32)(b0 | (b1 << 8) | (b2 << 16) | (b3 << 24));
    if (lane == 0) dqw[row] = m / (127.f * 127.f);
}

// ---------------- embedding gather + cast to f16 ----------------
__global__ void embed_k(const int* __restrict__ x, const float* __restrict__ emb,
                        _Float16* __restrict__ xe) {
    int m = blockIdx.x;                  // 0..32767 = b*T + t
    int row = x[m];
    int c = threadIdx.x * 4;             // 128 threads * 4 = 512
    float4 v = *(const float4*)(emb + (size_t)row * E_ + c);
    half2v p0; p0.x = (_Float16)v.x; p0.y = (_Float16)v.y;
    half2v p1; p1.x = (_Float16)v.z; p1.y = (_Float16)v.w;
    u32* dst = (u32*)(xe + (size_t)m * E_) + threadIdx.x * 2;
    dst[0] = __builtin_bit_cast(u32, p0);
    dst[1] = __builtin_bit_cast(u32, p1);
}

// ---------------- f16 MFMA GEMM:  C[m,n] = sum_k A[m,k]*Bw[n,k] + bias[n]  (C f16) -----
__global__ __launch_bounds__(256) void gemm_bt(const _Float16* __restrict__ A,
                                               const _Float16* __restrict__ Bw,
                                               const float* __restrict__ bsum,
                                               _Float16* __restrict__ C,
                                               int M, int N, int Kd) {
    __shared__ __align__(16) _Float16 As[128 * 64];
    __shared__ __align__(16) _Float16 Bs[128 * 64];
    const int nTn = N >> 7;
    const int tm = blockIdx.x / nTn, tn = blockIdx.x % nTn;
    const int tid = threadIdx.x;
    const int lane = tid & 63, wave = tid >> 6;
    const int wr = wave >> 1, wc = wave & 1;      // 2x2 waves of 64x64
    f32x4 acc[4][4];
#pragma unroll
    for (int i = 0; i < 4; ++i)
#pragma unroll
        for (int j = 0; j < 4; ++j) acc[i][j] = f32x4{0.f, 0.f, 0.f, 0.f};
    const int lr = lane & 15, lk = (lane >> 4) * 8;

    for (int k0 = 0; k0 < Kd; k0 += 64) {
#pragma unroll
        for (int r = 0; r < 4; ++r) {
            int c = r * 256 + tid;                     // chunk id, 16B each
            const _Float16* srcA = A + (size_t)(tm * 128 + (c >> 3)) * Kd + k0 + (c & 7) * 8;
            const _Float16* srcB = Bw + (size_t)(tn * 128 + (c >> 3)) * Kd + k0 + (c & 7) * 8;
            _Float16* dA = &As[(size_t)(r * 256 + wave * 64) * 8];
            _Float16* dB = &Bs[(size_t)(r * 256 + wave * 64) * 8];
            __builtin_amdgcn_global_load_lds((const __attribute__((address_space(1))) void*)srcA,
                                             (__attribute__((address_space(3))) void*)dA, 16, 0, 0);
            __builtin_amdgcn_global_load_lds((const __attribute__((address_space(1))) void*)srcB,
                                             (__attribute__((address_space(3))) void*)dB, 16, 0, 0);
        }
        __syncthreads();
#pragma unroll
        for (int kk = 0; kk < 2; ++kk) {
            half8 av[4], bv[4];
#pragma unroll
            for (int i = 0; i < 4; ++i)
                av[i] = *(const half8*)&As[(wr * 64 + i * 16 + lr) * 64 + kk * 32 + lk];
#pragma unroll
            for (int j = 0; j < 4; ++j)
                bv[j] = *(const half8*)&Bs[(wc * 64 + j * 16 + lr) * 64 + kk * 32 + lk];
#pragma unroll
            for (int i = 0; i < 4; ++i)
#pragma unroll
                for (int j = 0; j < 4; ++j)
                    acc[i][j] = __builtin_amdgcn_mfma_f32_16x16x32_f16(av[i], bv[j], acc[i][j], 0, 0, 0);
        }
        __syncthreads();
    }
    const int mq = (lane >> 4) * 4;
#pragma unroll
    for (int i = 0; i < 4; ++i)
#pragma unroll
        for (int j = 0; j < 4; ++j) {
            int m0 = tm * 128 + wr * 64 + i * 16 + mq;
            int n0 = tn * 128 + wc * 64 + j * 16 + lr;
            float bv = bsum[n0];
#pragma unroll
            for (int q = 0; q < 4; ++q)
                C[(size_t)(m0 + q) * N + n0] = (_Float16)(acc[i][j][q] + bv);
        }
}

// ---------------- LSTM recurrence: 512 threads, pair-split columns, 1 barrier/step ----
// Block = (b, dir), 128 blocks of 512 threads (8 waves = 2 waves/SIMD -- R8 lesson:
// 1 wave/SIMD exposes all latency; 2 is the sweet spot so far). Thread pair
// (lane l, lane l^32) owns unit v = wave*32 + (l&31): each thread computes ALL FOUR
// gate rows of v over HALF the columns (128 weight-u32, R7-proven allocatable).
// R7/R8 model: per-step cycles track LDS bytes at ~12 cyc/KB; h-broadcast replication
// is the bottleneck. Here each thread reads only 128 B of h -> 64 KB/block-step (was
// 128), partial dots are combined with ONE shfl_xor(32) per gate (z folded into half-0
// pre-exchange), gate math is thread-local (redundant in both halves) -> g_sh exchange
// and one of two barriers deleted.
__global__ __attribute__((amdgpu_flat_work_group_size(512, 512), amdgpu_waves_per_eu(2, 2)))
void lstm_layer_k(
    const u32* __restrict__ wq,           // [2][1024][64] packed i8 (this layer)
    const float* __restrict__ dqw,        // [2][1024] rowmax/127^2 (this layer)
    const float* __restrict__ h0,         // [2][64][256]
    const float* __restrict__ c0,         // [2][64][256]
    const _Float16* __restrict__ Z,       // [32768][2048] f16 preacts (x@Wih + bias)
    _Float16* __restrict__ Hout) {        // [32768][512] f16
    __shared__ __align__(16) u32 hbuf[2][64];   // i8 h, 256 units, parity double-buffer
    __shared__ float m0sh;
    const int tid = threadIdx.x;                 // 0..511
    const int b = blockIdx.x >> 1, dir = blockIdx.x & 1;
    const int w = tid >> 6, l = tid & 63;
    const int half = l >> 5;                     // column half
    const int v = w * 32 + (l & 31);             // unit 0..255

    // --- weights: 4 gate rows of unit v, column half, register-resident (32 uint4) ---
    const u32* wbase = wq + (size_t)dir * 1024 * 64;
    uint4 w0[8], w1[8], w2[8], w3[8];
#pragma unroll
    for (int k = 0; k < 8; ++k) {
        w0[k] = ((const uint4*)(wbase + (size_t)(0 * 256 + v) * 64 + half * 32))[k];
        w1[k] = ((const uint4*)(wbase + (size_t)(1 * 256 + v) * 64 + half * 32))[k];
        w2[k] = ((const uint4*)(wbase + (size_t)(2 * 256 + v) * 64 + half * 32))[k];
        w3[k] = ((const uint4*)(wbase + (size_t)(3 * 256 + v) * 64 + half * 32))[k];
    }
#pragma unroll
    for (int k = 0; k < 8; ++k) {
        asm("" : "+v"(w0[k].x), "+v"(w0[k].y), "+v"(w0[k].z), "+v"(w0[k].w));
        asm("" : "+v"(w1[k].x), "+v"(w1[k].y), "+v"(w1[k].z), "+v"(w1[k].w));
        asm("" : "+v"(w2[k].x), "+v"(w2[k].y), "+v"(w2[k].z), "+v"(w2[k].w));
        asm("" : "+v"(w3[k].x), "+v"(w3[k].y), "+v"(w3[k].z), "+v"(w3[k].w));
    }
    const float dq0 = dqw[dir * 1024 + 0 * 256 + v];
    const float dq1 = dqw[dir * 1024 + 1 * 256 + v];
    const float dq2 = dqw[dir * 1024 + 2 * 256 + v];
    const float dq3 = dqw[dir * 1024 + 3 * 256 + v];

    // --- state: c kept redundantly in both halves; h0 quantized by wave 0 ---
    float c = c0[(size_t)dir * B_ * HD_ + b * HD_ + v];
    if (tid < 64) {
        float4 hv = ((const float4*)(h0 + (size_t)dir * B_ * HD_ + (size_t)b * HD_))[tid];
        float am = fmaxf(fmaxf(fabsf(hv.x), fabsf(hv.y)), fmaxf(fabsf(hv.z), fabsf(hv.w)));
#pragma unroll
        for (int off = 32; off >= 1; off >>= 1) am = fmaxf(am, __shfl_xor(am, off, 64));
        am = fmaxf(am, 1e-6f);
        float sc = 127.f / am;
        int q0 = ((int)rintf(hv.x * sc)) & 255, q1 = ((int)rintf(hv.y * sc)) & 255;
        int q2 = ((int)rintf(hv.z * sc)) & 255, q3 = ((int)rintf(hv.w * sc)) & 255;
        hbuf[0][tid] = (u32)(q0 | (q1 << 8) | (q2 << 16) | (q3 << 24));
        if (tid == 0) m0sh = am;
    }
    // --- z: only half-0 threads load (folded pre-exchange); prefetched 1 step ahead ---
    const _Float16* Zr = Z + (size_t)b * T_ * 2048 + dir * 1024;
    const int t0 = dir ? (T_ - 1) : 0;
    float z0 = 0.f, z1 = 0.f, z2 = 0.f, z3 = 0.f;
    if (half == 0) {
        z0 = (float)Zr[(size_t)t0 * 2048 + 0 * 256 + v];
        z1 = (float)Zr[(size_t)t0 * 2048 + 1 * 256 + v];
        z2 = (float)Zr[(size_t)t0 * 2048 + 2 * 256 + v];
        z3 = (float)Zr[(size_t)t0 * 2048 + 3 * 256 + v];
    }
    __syncthreads();
    const float m0v = m0sh;
    float dqa = dq0 * m0v, dqb = dq1 * m0v, dqc = dq2 * m0v, dqd = dq3 * m0v;

    for (int s = 0; s < T_; ++s) {
        const int t = dir ? (T_ - 1 - s) : s;
        float zn0 = 0.f, zn1 = 0.f, zn2 = 0.f, zn3 = 0.f;
        if (half == 0 && s + 1 < T_) {
            const int tn = dir ? (t - 1) : (t + 1);
            zn0 = (float)Zr[(size_t)tn * 2048 + 0 * 256 + v];
            zn1 = (float)Zr[(size_t)tn * 2048 + 1 * 256 + v];
            zn2 = (float)Zr[(size_t)tn * 2048 + 2 * 256 + v];
            zn3 = (float)Zr[(size_t)tn * 2048 + 3 * 256 + v];
        }
        // --- 4 half-row dots (32 sdot4 each), 4 independent chains ---
        const uint4* hb = (const uint4*)&hbuf[s & 1][half * 32];
        uint4 hv[8];
#pragma unroll
        for (int k = 0; k < 8; ++k) hv[k] = hb[k];
        int p0 = 0, p1 = 0, p2 = 0, p3 = 0;
#pragma unroll
        for (int k = 0; k < 8; ++k) {
            p0 = dotq(w0[k], hv[k], p0);
            p1 = dotq(w1[k], hv[k], p1);
            p2 = dotq(w2[k], hv[k], p2);
            p3 = dotq(w3[k], hv[k], p3);
        }
        // dequant to float, fold z into half-0, then one exchange completes the dot
        float f0 = (float)p0 * dqa + z0;
        float f1 = (float)p1 * dqb + z1;
        float f2 = (float)p2 * dqc + z2;
        float f3 = (float)p3 * dqd + z3;
        f0 += __shfl_xor(f0, 32, 64);
        f1 += __shfl_xor(f1, 32, 64);
        f2 += __shfl_xor(f2, 32, 64);
        f3 += __shfl_xor(f3, 32, 64);
        // gates thread-local (redundant in both halves)
        c = sigm(f1) * c + sigm(f0) * tanh_f(f2);
        const float h = sigm(f3) * tanh_f(c);
        if (half == 0) {
            Hout[(size_t)(b * T_ + t) * H_ + dir * HD_ + v] = (_Float16)h;
            ((signed char*)&hbuf[(s + 1) & 1][0])[v] = (signed char)(int)rintf(h * 127.f);
        }
        if (s == 0) { dqa = dq0; dqb = dq1; dqc = dq2; dqd = dq3; }
        z0 = zn0; z1 = zn1; z2 = zn2; z3 = zn3;
        __syncthreads();                        // h(s+1) complete; single barrier/step
    }
}

// ---------------- tag scores: out[m,kk] = H[m,:] . w_out[kk,:] + b_out[kk] ----------------
__global__ __launch_bounds__(256) void tag_k(const _Float16* __restrict__ Hs,
                                             const float* __restrict__ wout,
                                             const float* __restrict__ bout,
                                             float* __restrict__ out) {
    const int tid = threadIdx.x;
    const int mi = tid >> 4, kk = tid & 15;
    const int m = blockIdx.x * 16 + mi;
    const uint4* hrow = (const uint4*)(Hs + (size_t)m * H_);
    const float4* wrow = (const float4*)(wout + (size_t)kk * H_);
    float acc = 0.f;
#pragma unroll 8
    for (int i = 0; i < 64; ++i) {
        uint4 hv = hrow[i];
        float4 w0 = wrow[2 * i], w1 = wrow[2 * i + 1];
        half2v p0 = __builtin_bit_cast(half2v, hv.x), p1 = __builtin_bit_cast(half2v, hv.y);
        half2v p2 = __builtin_bit_cast(half2v, hv.z), p3 = __builtin_bit_cast(half2v, hv.w);
        acc += (float)p0.x * w0.x + (float)p0.y * w0.y + (float)p1.x * w0.z + (float)p1.y * w0.w
             + (float)p2.x * w1.x + (float)p2.y * w1.y + (float)p3.x * w1.z + (float)p3.y * w1.w;
    }
    out[(size_t)m * K_ + kk] = acc + bout[kk];
}

// ---------------- CRF forward (faithful to reference's cross-batch sum) ----------------
__global__ __launch_bounds__(1024) void crf_k(const float* __restrict__ tag,
                                              const float* __restrict__ trans,
                                              float* __restrict__ out) {
    __shared__ float albuf[2][64][17];
    const int tid = threadIdx.x;
    const int kn = tid >> 6, b = tid & 63;   // wave = next-tag, lane = batch
    float trow[16];
#pragma unroll
    for (int kp = 0; kp < 16; ++kp) trow[kp] = trans[kn * 16 + kp];
    albuf[0][b][kn] = (kn == START_) ? 0.f : NEG_;
    __syncthreads();
    int cur = 0;
    for (int t = 0; t < T_; ++t) {
        const float feat = tag[(size_t)(b * T_ + t) * K_ + kn];
        float v[16];
        float m = -3.4e38f;
#pragma unroll
        for (int kp = 0; kp < 16; ++kp) {
            v[kp] = albuf[cur][b][kp] + trow[kp];
            m = fmaxf(m, v[kp]);
        }
        float sm = 0.f;
#pragma unroll
        for (int kp = 0; kp < 16; ++kp) sm += __expf(v[kp] - m);
#pragma unroll
        for (int off = 32; off >= 1; off >>= 1) sm += __shfl_xor(sm, off, 64);
        albuf[cur ^ 1][b][kn] = feat + m + __logf(sm);
        __syncthreads();
        cur ^= 1;
    }
    const float term = albuf[cur][b][kn] + trans[STOP_ * 16 + kn];
    albuf[cur ^ 1][b][kn] = term;
    __syncthreads();
    if (tid < 64) {   // all in wave 0
        float mb = -3.4e38f;
#pragma unroll
        for (int k2 = 0; k2 < 16; ++k2) mb = fmaxf(mb, albuf[cur ^ 1][tid][k2]);
        float p = 0.f;
#pragma unroll
        for (int k2 = 0; k2 < 16; ++k2) p += __expf(albuf[cur ^ 1][tid][k2] - mb);
#pragma unroll
        for (int off = 32; off >= 1; off >>= 1) p += __shfl_xor(p, off, 64);
        out[(size_t)B_ * T_ * K_ + tid] = mb + __logf(p);
    }
}

extern "C" void kernel_launch(void* const* d_in, const int* in_sizes, int n_in,
                              void* d_out, int out_size, void* d_ws, size_t ws_size,
                              hipStream_t stream) {
    const int*   x     = (const int*)d_in[0];
    const float* emb   = (const float*)d_in[2];
    const float* w_ih  = (const float*)d_in[3];
    const float* w_hh  = (const float*)d_in[4];
    const float* b_ih  = (const float*)d_in[5];
    const float* b_hh  = (const float*)d_in[6];
    const float* h0    = (const float*)d_in[7];
    const float* c0    = (const float*)d_in[8];
    const float* w_out = (const float*)d_in[9];
    const float* b_out = (const float*)d_in[10];
    const float* trans = (const float*)d_in[11];
    float* out = (float*)d_out;

    // workspace layout (≈199 MB)
    char* ws = (char*)d_ws;
    u32*      wq    = (u32*)ws;                                   // 1 MB   [L][2][1024][64] i8-packed
    float*    dqw   = (float*)(ws + ((size_t)1 << 20));           // 16 KB  [L][2][1024]
    _Float16* wih16 = (_Float16*)(ws + ((size_t)2 << 20));        // 4 MB   [L][2048][512]
    float*    bsum  = (float*)(ws + ((size_t)6 << 20));           // 16 KB  [L][2048]
    _Float16* xe    = (_Float16*)(ws + ((size_t)7 << 20));        // 32 MB  [32768][512] (reused as H1)
    _Float16* Zb    = (_Float16*)(ws + ((size_t)39 << 20));       // 128 MB [32768][2048]
    _Float16* H0b   = (_Float16*)(ws + ((size_t)167 << 20));      // 32 MB  [32768][512]
    if (ws_size < ((size_t)199 << 20)) return;

    quant_whh_k<<<4096, 64, 0, stream>>>(w_hh, wq, dqw);
    cvt_f16_k<<<2048, 256, 0, stream>>>(w_ih, wih16, 2097152 / 4);
    bias_sum_k<<<16, 256, 0, stream>>>(b_ih, b_hh, bsum);
    embed_k<<<B_ * T_, 128, 0, stream>>>(x, emb, xe);

    // layer 0
    gemm_bt<<<(32768 / 128) * (2048 / 128), 256, 0, stream>>>(xe, wih16, bsum, Zb, 32768, 2048, 512);
    lstm_layer_k<<<128, 512, 0, stream>>>(wq, dqw, h0, c0, Zb, H0b);
    // layer 1
    gemm_bt<<<(32768 / 128) * (2048 / 128), 256, 0, stream>>>(H0b, wih16 + (size_t)2048 * 512, bsum + 2048, Zb, 32768, 2048, 512);
    lstm_layer_k<<<128, 512, 0, stream>>>(wq + (size_t)2048 * 64, dqw + 2048,
                                          h0 + 2 * B_ * HD_, c0 + 2 * B_ * HD_, Zb, xe /*H1*/);
    // emissions + CRF
    tag_k<<<32768 / 16, 256, 0, stream>>>(xe, w_out, b_out, out);
    crf_k<<<1, 1024, 0, stream>>>(out, trans, out);
}

// Round 10
// 1945.376 us; speedup vs baseline: 1.2086x; 1.1648x over previous
//
#include <hip/hip_runtime.h>

#define B_ 64
#define T_ 512
#define E_ 512
#define HD_ 256
#define H_ 512
#define K_ 16
#define NEG_ (-10000.0f)
#define START_ 13
#define STOP_ 14

typedef unsigned int u32;
using half8  = __attribute__((ext_vector_type(8))) _Float16;
using f32x4  = __attribute__((ext_vector_type(4))) float;
using half2v = __attribute__((ext_vector_type(2))) _Float16;

__device__ __forceinline__ int dot4i8(u32 a, u32 b, int c) {
#if __has_builtin(__builtin_amdgcn_sdot4)
    return __builtin_amdgcn_sdot4((int)a, (int)b, c, false);
#else
    int r = c;
#pragma unroll
    for (int i = 0; i < 4; ++i) {
        int xa = ((int)a << (24 - 8 * i)) >> 24;
        int xb = ((int)b << (24 - 8 * i)) >> 24;
        r += xa * xb;
    }
    return r;
#endif
}
__device__ __forceinline__ int dotq(uint4 w, uint4 h, int a) {
    a = dot4i8(w.x, h.x, a); a = dot4i8(w.y, h.y, a);
    a = dot4i8(w.z, h.z, a); a = dot4i8(w.w, h.w, a);
    return a;
}
__device__ __forceinline__ float sigm(float x) { return 1.f / (1.f + __expf(-x)); }
__device__ __forceinline__ float tanh_f(float x) {
    float a = fabsf(x);
    float e = __expf(-2.f * a);
    float t = (1.f - e) / (1.f + e);
    return x < 0.f ? -t : t;
}

// ---------------- converters ----------------
__global__ void cvt_f16_k(const float* __restrict__ src, _Float16* __restrict__ dst, int n4) {
    int i = blockIdx.x * blockDim.x + threadIdx.x;
    if (i < n4) {
        float4 v = ((const float4*)src)[i];
        half2v a; a.x = (_Float16)v.x; a.y = (_Float16)v.y;
        half2v b; b.x = (_Float16)v.z; b.y = (_Float16)v.w;
        ((u32*)dst)[2 * i]     = __builtin_bit_cast(u32, a);
        ((u32*)dst)[2 * i + 1] = __builtin_bit_cast(u32, b);
    }
}
__global__ void bias_sum_k(const float* __restrict__ bih, const float* __restrict__ bhh,
                           float* __restrict__ bs) {
    int i = blockIdx.x * blockDim.x + threadIdx.x;
    if (i < 4096) bs[i] = bih[i] + bhh[i];
}

// ---------------- W_hh row-scaled int8 quantization: one 64-thread block per row ------
__global__ void quant_whh_k(const float* __restrict__ whh,   // [4096][256]
                            u32* __restrict__ wq,            // [4096][64] packed i8
                            float* __restrict__ dqw) {       // [4096] dequant = rowmax/127^2
    const int row = blockIdx.x, lane = threadIdx.x;          // 64 lanes
    const float4 v = ((const float4*)(whh + (size_t)row * 256))[lane];
    float m = fmaxf(fmaxf(fabsf(v.x), fabsf(v.y)), fmaxf(fabsf(v.z), fabsf(v.w)));
#pragma unroll
    for (int off = 32; off >= 1; off >>= 1) m = fmaxf(m, __shfl_xor(m, off, 64));
    m = fmaxf(m, 1e-8f);
    const float s = 127.f / m;
    int b0 = ((int)rintf(v.x * s)) & 255;
    int b1 = ((int)rintf(v.y * s)) & 255;
    int b2 = ((int)rintf(v.z * s)) & 255;
    int b3 = ((int)rintf(v.w * s)) & 255;
    wq[(size_t)row * 64 + lane] = (u32)(b0 | (b1 << 8) | (b2 << 16) | (b3 << 24));
    if (lane == 0) dqw[row] = m / (127.f * 127.f);
}

// ---------------- embedding gather + cast to f16 ----------------
__global__ void embed_k(const int* __restrict__ x, const float* __restrict__ emb,
                        _Float16* __restrict__ xe) {
    int m = blockIdx.x;                  // 0..32767 = b*T + t
    int row = x[m];
    int c = threadIdx.x * 4;             // 128 threads * 4 = 512
    float4 v = *(const float4*)(emb + (size_t)row * E_ + c);
    half2v p0; p0.x = (_Float16)v.x; p0.y = (_Float16)v.y;
    half2v p1; p1.x = (_Float16)v.z; p1.y = (_Float16)v.w;
    u32* dst = (u32*)(xe + (size_t)m * E_) + threadIdx.x * 2;
    dst[0] = __builtin_bit_cast(u32, p0);
    dst[1] = __builtin_bit_cast(u32, p1);
}

// ---------------- f16 MFMA GEMM:  C[m,n] = sum_k A[m,k]*Bw[n,k] + bias[n]  (C f16) -----
// XCD-aware bijective swizzle (T1): nwg = 4096 (divisible by 8). Blocks with the same
// orig%8 run on one XCD and get a CONTIGUOUS idx range -> all 16 tn-blocks of a given
// tm-panel execute on the same XCD, so the 128 KB A-panel is read from HBM once and
// re-read 15x from that XCD's L2 (was: round-robin scattered the panel across 8 XCDs,
// ~512 MB of redundant A traffic per layer). B (2 MB) is L2-resident everywhere.
__global__ __launch_bounds__(256) void gemm_bt(const _Float16* __restrict__ A,
                                               const _Float16* __restrict__ Bw,
                                               const float* __restrict__ bsum,
                                               _Float16* __restrict__ C,
                                               int M, int N, int Kd) {
    __shared__ __align__(16) _Float16 As[128 * 64];
    __shared__ __align__(16) _Float16 Bs[128 * 64];
    const int nTn = N >> 7;
    const int nwg = gridDim.x;
    const int idx = (blockIdx.x & 7) * (nwg >> 3) + (blockIdx.x >> 3);
    const int tm = idx / nTn, tn = idx % nTn;
    const int tid = threadIdx.x;
    const int lane = tid & 63, wave = tid >> 6;
    const int wr = wave >> 1, wc = wave & 1;      // 2x2 waves of 64x64
    f32x4 acc[4][4];
#pragma unroll
    for (int i = 0; i < 4; ++i)
#pragma unroll
        for (int j = 0; j < 4; ++j) acc[i][j] = f32x4{0.f, 0.f, 0.f, 0.f};
    const int lr = lane & 15, lk = (lane >> 4) * 8;

    for (int k0 = 0; k0 < Kd; k0 += 64) {
#pragma unroll
        for (int r = 0; r < 4; ++r) {
            int c = r * 256 + tid;                     // chunk id, 16B each
            const _Float16* srcA = A + (size_t)(tm * 128 + (c >> 3)) * Kd + k0 + (c & 7) * 8;
            const _Float16* srcB = Bw + (size_t)(tn * 128 + (c >> 3)) * Kd + k0 + (c & 7) * 8;
            _Float16* dA = &As[(size_t)(r * 256 + wave * 64) * 8];
            _Float16* dB = &Bs[(size_t)(r * 256 + wave * 64) * 8];
            __builtin_amdgcn_global_load_lds((const __attribute__((address_space(1))) void*)srcA,
                                             (__attribute__((address_space(3))) void*)dA, 16, 0, 0);
            __builtin_amdgcn_global_load_lds((const __attribute__((address_space(1))) void*)srcB,
                                             (__attribute__((address_space(3))) void*)dB, 16, 0, 0);
        }
        __syncthreads();
#pragma unroll
        for (int kk = 0; kk < 2; ++kk) {
            half8 av[4], bv[4];
#pragma unroll
            for (int i = 0; i < 4; ++i)
                av[i] = *(const half8*)&As[(wr * 64 + i * 16 + lr) * 64 + kk * 32 + lk];
#pragma unroll
            for (int j = 0; j < 4; ++j)
                bv[j] = *(const half8*)&Bs[(wc * 64 + j * 16 + lr) * 64 + kk * 32 + lk];
#pragma unroll
            for (int i = 0; i < 4; ++i)
#pragma unroll
                for (int j = 0; j < 4; ++j)
                    acc[i][j] = __builtin_amdgcn_mfma_f32_16x16x32_f16(av[i], bv[j], acc[i][j], 0, 0, 0);
        }
        __syncthreads();
    }
    const int mq = (lane >> 4) * 4;
#pragma unroll
    for (int i = 0; i < 4; ++i)
#pragma unroll
        for (int j = 0; j < 4; ++j) {
            int m0 = tm * 128 + wr * 64 + i * 16 + mq;
            int n0 = tn * 128 + wc * 64 + j * 16 + lr;
            float bv = bsum[n0];
#pragma unroll
            for (int q = 0; q < 4; ++q)
                C[(size_t)(m0 + q) * N + n0] = (_Float16)(acc[i][j][q] + bv);
        }
}

// ---------------- LSTM recurrence (R7-proven, 556us): 512 threads, 2 full rows/thread --
// Block = (b, dir), 128 blocks of 512 threads (8 waves = 2 waves/SIMD). Thread u owns
// FULL 256-col rows u and u+512. Full-row dots => no cross-lane ops anywhere in the
// step loop (R9 lesson: dependent shuffles cost ~150-190 cyc each), uniform-address
// LDS reads broadcast cheaply (R9 falsified the replication-bandwidth theory).
__global__ __attribute__((amdgpu_flat_work_group_size(512, 512), amdgpu_waves_per_eu(2, 2)))
void lstm_layer_k(
    const u32* __restrict__ wq,           // [2][1024][64] packed i8 (this layer)
    const float* __restrict__ dqw,        // [2][1024] rowmax/127^2 (this layer)
    const float* __restrict__ h0,         // [2][64][256]
    const float* __restrict__ c0,         // [2][64][256]
    const _Float16* __restrict__ Z,       // [32768][2048] f16 preacts (x@Wih + bias)
    _Float16* __restrict__ Hout) {        // [32768][512] f16
    __shared__ __align__(16) u32 hbuf[2][64];   // i8 h, 256 units, parity double-buffer
    __shared__ float g_sh[1024];
    __shared__ float m0sh;
    const int tid = threadIdx.x;                 // 0..511
    const int b = blockIdx.x >> 1, dir = blockIdx.x & 1;
    const int R0 = tid, R1 = tid + 512;

    // --- weights: two full rows, register-resident (16+16 uint4) ---
    const uint4* w4 = (const uint4*)(wq + (size_t)dir * 1024 * 64);
    uint4 wa[16], wb[16];
#pragma unroll
    for (int i = 0; i < 16; ++i) wa[i] = w4[(size_t)R0 * 16 + i];
#pragma unroll
    for (int i = 0; i < 16; ++i) wb[i] = w4[(size_t)R1 * 16 + i];
    // keep-live: compiler must hold these (not re-load from global each step)
#pragma unroll
    for (int i = 0; i < 16; ++i) {
        asm volatile("" : "+v"(wa[i].x), "+v"(wa[i].y), "+v"(wa[i].z), "+v"(wa[i].w));
        asm volatile("" : "+v"(wb[i].x), "+v"(wb[i].y), "+v"(wb[i].z), "+v"(wb[i].w));
    }
    const float dq0 = dqw[dir * 1024 + R0];
    const float dq1 = dqw[dir * 1024 + R1];

    // --- state: threads 0..255 own c[unit]; wave 0 quantizes h0 with dynamic scale ---
    float c = 0.f;
    if (tid < 256) c = c0[(size_t)dir * B_ * HD_ + b * HD_ + tid];
    if (tid < 64) {
        float4 hv = ((const float4*)(h0 + (size_t)dir * B_ * HD_ + (size_t)b * HD_))[tid];
        float am = fmaxf(fmaxf(fabsf(hv.x), fabsf(hv.y)), fmaxf(fabsf(hv.z), fabsf(hv.w)));
#pragma unroll
        for (int off = 32; off >= 1; off >>= 1) am = fmaxf(am, __shfl_xor(am, off, 64));
        am = fmaxf(am, 1e-6f);
        float sc = 127.f / am;
        int q0 = ((int)rintf(hv.x * sc)) & 255, q1 = ((int)rintf(hv.y * sc)) & 255;
        int q2 = ((int)rintf(hv.z * sc)) & 255, q3 = ((int)rintf(hv.w * sc)) & 255;
        hbuf[0][tid] = (u32)(q0 | (q1 << 8) | (q2 << 16) | (q3 << 24));
        if (tid == 0) m0sh = am;
    }
    // --- z: this thread's two rows, prefetched one step ahead (coalesced) ---
    const _Float16* Zr = Z + (size_t)b * T_ * 2048 + dir * 1024;
    const int t0 = dir ? (T_ - 1) : 0;
    float z0 = (float)Zr[(size_t)t0 * 2048 + R0];
    float z1 = (float)Zr[(size_t)t0 * 2048 + R1];
    __syncthreads();
    const float m0v = m0sh;

    for (int s = 0; s < T_; ++s) {
        const int t = dir ? (T_ - 1 - s) : s;
        float zn0 = 0.f, zn1 = 0.f;
        if (s + 1 < T_) {
            const int tn = dir ? (t - 1) : (t + 1);
            zn0 = (float)Zr[(size_t)tn * 2048 + R0];
            zn1 = (float)Zr[(size_t)tn * 2048 + R1];
        }
        // --- two full-row dots: 32 sdot4 each, h via broadcast b128 reads ---
        const uint4* hb = (const uint4*)&hbuf[s & 1][0];
        int a0 = 0, a1 = 0;
#pragma unroll
        for (int i = 0; i < 16; ++i) {
            uint4 hv = hb[i];
            a0 = dotq(wa[i], hv, a0);
            a1 = dotq(wb[i], hv, a1);
        }
        const float sc = (s == 0) ? m0v : 1.f;
        g_sh[R0] = (float)a0 * (dq0 * sc) + z0;
        g_sh[R1] = (float)a1 * (dq1 * sc) + z1;
        z0 = zn0; z1 = zn1;
        __syncthreads();                        // preacts ready
        if (tid < 256) {
            float gi = g_sh[tid], gf = g_sh[tid + 256];
            float gg = g_sh[tid + 512], go = g_sh[tid + 768];
            c = sigm(gf) * c + sigm(gi) * tanh_f(gg);
            float h = sigm(go) * tanh_f(c);
            Hout[(size_t)(b * T_ + t) * H_ + dir * HD_ + tid] = (_Float16)h;
            ((signed char*)&hbuf[(s + 1) & 1][0])[tid] = (signed char)(int)rintf(h * 127.f);
        }
        __syncthreads();                        // h(s+1) complete
    }
}

// ---------------- tag scores: out[m,kk] = H[m,:] . w_out[kk,:] + b_out[kk] ----------------
__global__ __launch_bounds__(256) void tag_k(const _Float16* __restrict__ Hs,
                                             const float* __restrict__ wout,
                                             const float* __restrict__ bout,
                                             float* __restrict__ out) {
    const int tid = threadIdx.x;
    const int mi = tid >> 4, kk = tid & 15;
    const int m = blockIdx.x * 16 + mi;
    const uint4* hrow = (const uint4*)(Hs + (size_t)m * H_);
    const float4* wrow = (const float4*)(wout + (size_t)kk * H_);
    float acc = 0.f;
#pragma unroll 8
    for (int i = 0; i < 64; ++i) {
        uint4 hv = hrow[i];
        float4 w0 = wrow[2 * i], w1 = wrow[2 * i + 1];
        half2v p0 = __builtin_bit_cast(half2v, hv.x), p1 = __builtin_bit_cast(half2v, hv.y);
        half2v p2 = __builtin_bit_cast(half2v, hv.z), p3 = __builtin_bit_cast(half2v, hv.w);
        acc += (float)p0.x * w0.x + (float)p0.y * w0.y + (float)p1.x * w0.z + (float)p1.y * w0.w
             + (float)p2.x * w1.x + (float)p2.y * w1.y + (float)p3.x * w1.z + (float)p3.y * w1.w;
    }
    out[(size_t)m * K_ + kk] = acc + bout[kk];
}

// ---------------- CRF forward (faithful to reference's cross-batch sum) ----------------
__global__ __launch_bounds__(1024) void crf_k(const float* __restrict__ tag,
                                              const float* __restrict__ trans,
                                              float* __restrict__ out) {
    __shared__ float albuf[2][64][17];
    const int tid = threadIdx.x;
    const int kn = tid >> 6, b = tid & 63;   // wave = next-tag, lane = batch
    float trow[16];
#pragma unroll
    for (int kp = 0; kp < 16; ++kp) trow[kp] = trans[kn * 16 + kp];
    albuf[0][b][kn] = (kn == START_) ? 0.f : NEG_;
    __syncthreads();
    int cur = 0;
    for (int t = 0; t < T_; ++t) {
        const float feat = tag[(size_t)(b * T_ + t) * K_ + kn];
        float v[16];
        float m = -3.4e38f;
#pragma unroll
        for (int kp = 0; kp < 16; ++kp) {
            v[kp] = albuf[cur][b][kp] + trow[kp];
            m = fmaxf(m, v[kp]);
        }
        float sm = 0.f;
#pragma unroll
        for (int kp = 0; kp < 16; ++kp) sm += __expf(v[kp] - m);
#pragma unroll
        for (int off = 32; off >= 1; off >>= 1) sm += __shfl_xor(sm, off, 64);
        albuf[cur ^ 1][b][kn] = feat + m + __logf(sm);
        __syncthreads();
        cur ^= 1;
    }
    const float term = albuf[cur][b][kn] + trans[STOP_ * 16 + kn];
    albuf[cur ^ 1][b][kn] = term;
    __syncthreads();
    if (tid < 64) {   // all in wave 0
        float mb = -3.4e38f;
#pragma unroll
        for (int k2 = 0; k2 < 16; ++k2) mb = fmaxf(mb, albuf[cur ^ 1][tid][k2]);
        float p = 0.f;
#pragma unroll
        for (int k2 = 0; k2 < 16; ++k2) p += __expf(albuf[cur ^ 1][tid][k2] - mb);
#pragma unroll
        for (int off = 32; off >= 1; off >>= 1) p += __shfl_xor(p, off, 64);
        out[(size_t)B_ * T_ * K_ + tid] = mb + __logf(p);
    }
}

extern "C" void kernel_launch(void* const* d_in, const int* in_sizes, int n_in,
                              void* d_out, int out_size, void* d_ws, size_t ws_size,
                              hipStream_t stream) {
    const int*   x     = (const int*)d_in[0];
    const float* emb   = (const float*)d_in[2];
    const float* w_ih  = (const float*)d_in[3];
    const float* w_hh  = (const float*)d_in[4];
    const float* b_ih  = (const float*)d_in[5];
    const float* b_hh  = (const float*)d_in[6];
    const float* h0    = (const float*)d_in[7];
    const float* c0    = (const float*)d_in[8];
    const float* w_out = (const float*)d_in[9];
    const float* b_out = (const float*)d_in[10];
    const float* trans = (const float*)d_in[11];
    float* out = (float*)d_out;

    // workspace layout (≈199 MB)
    char* ws = (char*)d_ws;
    u32*      wq    = (u32*)ws;                                   // 1 MB   [L][2][1024][64] i8-packed
    float*    dqw   = (float*)(ws + ((size_t)1 << 20));           // 16 KB  [L][2][1024]
    _Float16* wih16 = (_Float16*)(ws + ((size_t)2 << 20));        // 4 MB   [L][2048][512]
    float*    bsum  = (float*)(ws + ((size_t)6 << 20));           // 16 KB  [L][2048]
    _Float16* xe    = (_Float16*)(ws + ((size_t)7 << 20));        // 32 MB  [32768][512] (reused as H1)
    _Float16* Zb    = (_Float16*)(ws + ((size_t)39 << 20));       // 128 MB [32768][2048]
    _Float16* H0b   = (_Float16*)(ws + ((size_t)167 << 20));      // 32 MB  [32768][512]
    if (ws_size < ((size_t)199 << 20)) return;

    quant_whh_k<<<4096, 64, 0, stream>>>(w_hh, wq, dqw);
    cvt_f16_k<<<2048, 256, 0, stream>>>(w_ih, wih16, 2097152 / 4);
    bias_sum_k<<<16, 256, 0, stream>>>(b_ih, b_hh, bsum);
    embed_k<<<B_ * T_, 128, 0, stream>>>(x, emb, xe);

    // layer 0
    gemm_bt<<<(32768 / 128) * (2048 / 128), 256, 0, stream>>>(xe, wih16, bsum, Zb, 32768, 2048, 512);
    lstm_layer_k<<<128, 512, 0, stream>>>(wq, dqw, h0, c0, Zb, H0b);
    // layer 1
    gemm_bt<<<(32768 / 128) * (2048 / 128), 256, 0, stream>>>(H0b, wih16 + (size_t)2048 * 512, bsum + 2048, Zb, 32768, 2048, 512);
    lstm_layer_k<<<128, 512, 0, stream>>>(wq + (size_t)2048 * 64, dqw + 2048,
                                          h0 + 2 * B_ * HD_, c0 + 2 * B_ * HD_, Zb, xe /*H1*/);
    // emissions + CRF
    tag_k<<<32768 / 16, 256, 0, stream>>>(xe, w_out, b_out, out);
    crf_k<<<1, 1024, 0, stream>>>(out, trans, out);
}

// Round 11
// 1879.580 us; speedup vs baseline: 1.2509x; 1.0350x over previous
//
#include <hip/hip_runtime.h>

#define B_ 64
#define T_ 512
#define E_ 512
#define HD_ 256
#define H_ 512
#define K_ 16
#define NEG_ (-10000.0f)
#define START_ 13
#define STOP_ 14

typedef unsigned int u32;
using half8  = __attribute__((ext_vector_type(8))) _Float16;
using f32x4  = __attribute__((ext_vector_type(4))) float;
using half2v = __attribute__((ext_vector_type(2))) _Float16;

__device__ __forceinline__ int dot4i8(u32 a, u32 b, int c) {
#if __has_builtin(__builtin_amdgcn_sdot4)
    return __builtin_amdgcn_sdot4((int)a, (int)b, c, false);
#else
    int r = c;
#pragma unroll
    for (int i = 0; i < 4; ++i) {
        int xa = ((int)a << (24 - 8 * i)) >> 24;
        int xb = ((int)b << (24 - 8 * i)) >> 24;
        r += xa * xb;
    }
    return r;
#endif
}
__device__ __forceinline__ int dotq(uint4 w, uint4 h, int a) {
    a = dot4i8(w.x, h.x, a); a = dot4i8(w.y, h.y, a);
    a = dot4i8(w.z, h.z, a); a = dot4i8(w.w, h.w, a);
    return a;
}
__device__ __forceinline__ float sigm(float x) { return 1.f / (1.f + __expf(-x)); }
__device__ __forceinline__ float tanh_f(float x) {
    float a = fabsf(x);
    float e = __expf(-2.f * a);
    float t = (1.f - e) / (1.f + e);
    return x < 0.f ? -t : t;
}

// Canonical GCN/CDNA wave64 sum via DPP (VALU pipe — no LDS traffic, unlike
// __shfl_xor's ds_bpermute). row_shr:1/2/4/8 -> lane15 of each 16-row holds row sum;
// row_bcast:15 folds row0->row1 (lane31 = sum 0-31) and row2->row3 (lane63 = 32-63);
// row_bcast:31 folds lower half into upper (lane63 = total). bound_ctrl=1: OOB reads 0.
__device__ __forceinline__ float wave_sum64(float x) {
#if __has_builtin(__builtin_amdgcn_update_dpp)
#define DPPADD_(ctrl)                                                                  \
    x += __builtin_bit_cast(float, __builtin_amdgcn_update_dpp(                        \
             0, __builtin_bit_cast(int, x), ctrl, 0xf, 0xf, true))
    DPPADD_(0x111); DPPADD_(0x112); DPPADD_(0x114); DPPADD_(0x118);
    DPPADD_(0x142); DPPADD_(0x143);
#undef DPPADD_
    return __builtin_bit_cast(float, __builtin_amdgcn_readlane(__builtin_bit_cast(int, x), 63));
#else
#pragma unroll
    for (int off = 32; off >= 1; off >>= 1) x += __shfl_xor(x, off, 64);
    return x;
#endif
}

// ---------------- converters ----------------
__global__ void cvt_f16_k(const float* __restrict__ src, _Float16* __restrict__ dst, int n4) {
    int i = blockIdx.x * blockDim.x + threadIdx.x;
    if (i < n4) {
        float4 v = ((const float4*)src)[i];
        half2v a; a.x = (_Float16)v.x; a.y = (_Float16)v.y;
        half2v b; b.x = (_Float16)v.z; b.y = (_Float16)v.w;
        ((u32*)dst)[2 * i]     = __builtin_bit_cast(u32, a);
        ((u32*)dst)[2 * i + 1] = __builtin_bit_cast(u32, b);
    }
}
__global__ void bias_sum_k(const float* __restrict__ bih, const float* __restrict__ bhh,
                           float* __restrict__ bs) {
    int i = blockIdx.x * blockDim.x + threadIdx.x;
    if (i < 4096) bs[i] = bih[i] + bhh[i];
}

// ---------------- W_hh row-scaled int8 quantization: one 64-thread block per row ------
__global__ void quant_whh_k(const float* __restrict__ whh,   // [4096][256]
                            u32* __restrict__ wq,            // [4096][64] packed i8
                            float* __restrict__ dqw) {       // [4096] dequant = rowmax/127^2
    const int row = blockIdx.x, lane = threadIdx.x;          // 64 lanes
    const float4 v = ((const float4*)(whh + (size_t)row * 256))[lane];
    float m = fmaxf(fmaxf(fabsf(v.x), fabsf(v.y)), fmaxf(fabsf(v.z), fabsf(v.w)));
#pragma unroll
    for (int off = 32; off >= 1; off >>= 1) m = fmaxf(m, __shfl_xor(m, off, 64));
    m = fmaxf(m, 1e-8f);
    const float s = 127.f / m;
    int b0 = ((int)rintf(v.x * s)) & 255;
    int b1 = ((int)rintf(v.y * s)) & 255;
    int b2 = ((int)rintf(v.z * s)) & 255;
    int b3 = ((int)rintf(v.w * s)) & 255;
    wq[(size_t)row * 64 + lane] = (u32)(b0 | (b1 << 8) | (b2 << 16) | (b3 << 24));
    if (lane == 0) dqw[row] = m / (127.f * 127.f);
}

// ---------------- embedding gather + cast to f16 ----------------
__global__ void embed_k(const int* __restrict__ x, const float* __restrict__ emb,
                        _Float16* __restrict__ xe) {
    int m = blockIdx.x;                  // 0..32767 = b*T + t
    int row = x[m];
    int c = threadIdx.x * 4;             // 128 threads * 4 = 512
    float4 v = *(const float4*)(emb + (size_t)row * E_ + c);
    half2v p0; p0.x = (_Float16)v.x; p0.y = (_Float16)v.y;
    half2v p1; p1.x = (_Float16)v.z; p1.y = (_Float16)v.w;
    u32* dst = (u32*)(xe + (size_t)m * E_) + threadIdx.x * 2;
    dst[0] = __builtin_bit_cast(u32, p0);
    dst[1] = __builtin_bit_cast(u32, p1);
}

// ---------------- f16 MFMA GEMM:  C[m,n] = sum_k A[m,k]*Bw[n,k] + bias[n]  (C f16) -----
__global__ __launch_bounds__(256) void gemm_bt(const _Float16* __restrict__ A,
                                               const _Float16* __restrict__ Bw,
                                               const float* __restrict__ bsum,
                                               _Float16* __restrict__ C,
                                               int M, int N, int Kd) {
    __shared__ __align__(16) _Float16 As[128 * 64];
    __shared__ __align__(16) _Float16 Bs[128 * 64];
    const int nTn = N >> 7;
    const int nwg = gridDim.x;
    const int idx = (blockIdx.x & 7) * (nwg >> 3) + (blockIdx.x >> 3);
    const int tm = idx / nTn, tn = idx % nTn;
    const int tid = threadIdx.x;
    const int lane = tid & 63, wave = tid >> 6;
    const int wr = wave >> 1, wc = wave & 1;      // 2x2 waves of 64x64
    f32x4 acc[4][4];
#pragma unroll
    for (int i = 0; i < 4; ++i)
#pragma unroll
        for (int j = 0; j < 4; ++j) acc[i][j] = f32x4{0.f, 0.f, 0.f, 0.f};
    const int lr = lane & 15, lk = (lane >> 4) * 8;

    for (int k0 = 0; k0 < Kd; k0 += 64) {
#pragma unroll
        for (int r = 0; r < 4; ++r) {
            int c = r * 256 + tid;                     // chunk id, 16B each
            const _Float16* srcA = A + (size_t)(tm * 128 + (c >> 3)) * Kd + k0 + (c & 7) * 8;
            const _Float16* srcB = Bw + (size_t)(tn * 128 + (c >> 3)) * Kd + k0 + (c & 7) * 8;
            _Float16* dA = &As[(size_t)(r * 256 + wave * 64) * 8];
            _Float16* dB = &Bs[(size_t)(r * 256 + wave * 64) * 8];
            __builtin_amdgcn_global_load_lds((const __attribute__((address_space(1))) void*)srcA,
                                             (__attribute__((address_space(3))) void*)dA, 16, 0, 0);
            __builtin_amdgcn_global_load_lds((const __attribute__((address_space(1))) void*)srcB,
                                             (__attribute__((address_space(3))) void*)dB, 16, 0, 0);
        }
        __syncthreads();
#pragma unroll
        for (int kk = 0; kk < 2; ++kk) {
            half8 av[4], bv[4];
#pragma unroll
            for (int i = 0; i < 4; ++i)
                av[i] = *(const half8*)&As[(wr * 64 + i * 16 + lr) * 64 + kk * 32 + lk];
#pragma unroll
            for (int j = 0; j < 4; ++j)
                bv[j] = *(const half8*)&Bs[(wc * 64 + j * 16 + lr) * 64 + kk * 32 + lk];
#pragma unroll
            for (int i = 0; i < 4; ++i)
#pragma unroll
                for (int j = 0; j < 4; ++j)
                    acc[i][j] = __builtin_amdgcn_mfma_f32_16x16x32_f16(av[i], bv[j], acc[i][j], 0, 0, 0);
        }
        __syncthreads();
    }
    const int mq = (lane >> 4) * 4;
#pragma unroll
    for (int i = 0; i < 4; ++i)
#pragma unroll
        for (int j = 0; j < 4; ++j) {
            int m0 = tm * 128 + wr * 64 + i * 16 + mq;
            int n0 = tn * 128 + wc * 64 + j * 16 + lr;
            float bv = bsum[n0];
#pragma unroll
            for (int q = 0; q < 4; ++q)
                C[(size_t)(m0 + q) * N + n0] = (_Float16)(acc[i][j][q] + bv);
        }
}

// ---------------- LSTM recurrence (R7-proven, 556us): 512 threads, 2 full rows/thread --
__global__ __attribute__((amdgpu_flat_work_group_size(512, 512), amdgpu_waves_per_eu(2, 2)))
void lstm_layer_k(
    const u32* __restrict__ wq,           // [2][1024][64] packed i8 (this layer)
    const float* __restrict__ dqw,        // [2][1024] rowmax/127^2 (this layer)
    const float* __restrict__ h0,         // [2][64][256]
    const float* __restrict__ c0,         // [2][64][256]
    const _Float16* __restrict__ Z,       // [32768][2048] f16 preacts (x@Wih + bias)
    _Float16* __restrict__ Hout) {        // [32768][512] f16
    __shared__ __align__(16) u32 hbuf[2][64];   // i8 h, 256 units, parity double-buffer
    __shared__ float g_sh[1024];
    __shared__ float m0sh;
    const int tid = threadIdx.x;                 // 0..511
    const int b = blockIdx.x >> 1, dir = blockIdx.x & 1;
    const int R0 = tid, R1 = tid + 512;

    const uint4* w4 = (const uint4*)(wq + (size_t)dir * 1024 * 64);
    uint4 wa[16], wb[16];
#pragma unroll
    for (int i = 0; i < 16; ++i) wa[i] = w4[(size_t)R0 * 16 + i];
#pragma unroll
    for (int i = 0; i < 16; ++i) wb[i] = w4[(size_t)R1 * 16 + i];
#pragma unroll
    for (int i = 0; i < 16; ++i) {
        asm volatile("" : "+v"(wa[i].x), "+v"(wa[i].y), "+v"(wa[i].z), "+v"(wa[i].w));
        asm volatile("" : "+v"(wb[i].x), "+v"(wb[i].y), "+v"(wb[i].z), "+v"(wb[i].w));
    }
    const float dq0 = dqw[dir * 1024 + R0];
    const float dq1 = dqw[dir * 1024 + R1];

    float c = 0.f;
    if (tid < 256) c = c0[(size_t)dir * B_ * HD_ + b * HD_ + tid];
    if (tid < 64) {
        float4 hv = ((const float4*)(h0 + (size_t)dir * B_ * HD_ + (size_t)b * HD_))[tid];
        float am = fmaxf(fmaxf(fabsf(hv.x), fabsf(hv.y)), fmaxf(fabsf(hv.z), fabsf(hv.w)));
#pragma unroll
        for (int off = 32; off >= 1; off >>= 1) am = fmaxf(am, __shfl_xor(am, off, 64));
        am = fmaxf(am, 1e-6f);
        float sc = 127.f / am;
        int q0 = ((int)rintf(hv.x * sc)) & 255, q1 = ((int)rintf(hv.y * sc)) & 255;
        int q2 = ((int)rintf(hv.z * sc)) & 255, q3 = ((int)rintf(hv.w * sc)) & 255;
        hbuf[0][tid] = (u32)(q0 | (q1 << 8) | (q2 << 16) | (q3 << 24));
        if (tid == 0) m0sh = am;
    }
    const _Float16* Zr = Z + (size_t)b * T_ * 2048 + dir * 1024;
    const int t0 = dir ? (T_ - 1) : 0;
    float z0 = (float)Zr[(size_t)t0 * 2048 + R0];
    float z1 = (float)Zr[(size_t)t0 * 2048 + R1];
    __syncthreads();
    const float m0v = m0sh;

    for (int s = 0; s < T_; ++s) {
        const int t = dir ? (T_ - 1 - s) : s;
        float zn0 = 0.f, zn1 = 0.f;
        if (s + 1 < T_) {
            const int tn = dir ? (t - 1) : (t + 1);
            zn0 = (float)Zr[(size_t)tn * 2048 + R0];
            zn1 = (float)Zr[(size_t)tn * 2048 + R1];
        }
        const uint4* hb = (const uint4*)&hbuf[s & 1][0];
        int a0 = 0, a1 = 0;
#pragma unroll
        for (int i = 0; i < 16; ++i) {
            uint4 hv = hb[i];
            a0 = dotq(wa[i], hv, a0);
            a1 = dotq(wb[i], hv, a1);
        }
        const float sc = (s == 0) ? m0v : 1.f;
        g_sh[R0] = (float)a0 * (dq0 * sc) + z0;
        g_sh[R1] = (float)a1 * (dq1 * sc) + z1;
        z0 = zn0; z1 = zn1;
        __syncthreads();                        // preacts ready
        if (tid < 256) {
            float gi = g_sh[tid], gf = g_sh[tid + 256];
            float gg = g_sh[tid + 512], go = g_sh[tid + 768];
            c = sigm(gf) * c + sigm(gi) * tanh_f(gg);
            float h = sigm(go) * tanh_f(c);
            Hout[(size_t)(b * T_ + t) * H_ + dir * HD_ + tid] = (_Float16)h;
            ((signed char*)&hbuf[(s + 1) & 1][0])[tid] = (signed char)(int)rintf(h * 127.f);
        }
        __syncthreads();                        // h(s+1) complete
    }
}

// ---------------- tag scores: out[m,kk] = H[m,:] . w_out[kk,:] + b_out[kk] ----------------
__global__ __launch_bounds__(256) void tag_k(const _Float16* __restrict__ Hs,
                                             const float* __restrict__ wout,
                                             const float* __restrict__ bout,
                                             float* __restrict__ out) {
    const int tid = threadIdx.x;
    const int mi = tid >> 4, kk = tid & 15;
    const int m = blockIdx.x * 16 + mi;
    const uint4* hrow = (const uint4*)(Hs + (size_t)m * H_);
    const float4* wrow = (const float4*)(wout + (size_t)kk * H_);
    float acc = 0.f;
#pragma unroll 8
    for (int i = 0; i < 64; ++i) {
        uint4 hv = hrow[i];
        float4 w0 = wrow[2 * i], w1 = wrow[2 * i + 1];
        half2v p0 = __builtin_bit_cast(half2v, hv.x), p1 = __builtin_bit_cast(half2v, hv.y);
        half2v p2 = __builtin_bit_cast(half2v, hv.z), p3 = __builtin_bit_cast(half2v, hv.w);
        acc += (float)p0.x * w0.x + (float)p0.y * w0.y + (float)p1.x * w0.z + (float)p1.y * w0.w
             + (float)p2.x * w1.x + (float)p2.y * w1.y + (float)p3.x * w1.z + (float)p3.y * w1.w;
    }
    out[(size_t)m * K_ + kk] = acc + bout[kk];
}

// ---------------- CRF forward (faithful to reference's cross-batch sum) ----------------
// R11: LDS-pipe diet on the single-CU sequential kernel. Per step per thread:
// was 16 ds_read_b32 (unaligned [17] rows) + 6 ds_bpermute (shfl) + 1 write = 23 LDS ops
// x 16 waves = 368 LDS instr/step on ONE CU's LDS pipe (~2200 cyc/step, the bottleneck).
// Now: [64][20] rows (16B-aligned) -> 4 float4 reads; DPP wave-sum (VALU pipe, 0 LDS);
// feat prefetched one step ahead. LDS instr/step: 368 -> 80.
__global__ __launch_bounds__(1024) void crf_k(const float* __restrict__ tag,
                                              const float* __restrict__ trans,
                                              float* __restrict__ out) {
    __shared__ __align__(16) float albuf[2][64][20];
    const int tid = threadIdx.x;
    const int kn = tid >> 6, b = tid & 63;   // wave = next-tag, lane = batch
    float trow[16];
#pragma unroll
    for (int kp = 0; kp < 16; ++kp) trow[kp] = trans[kn * 16 + kp];
    if (kn < 2) {   // threads 0..127 init both parity buffers' used columns? only [0] needed
        // init albuf[0][b][0..15]: thread (kn,b) with kn<... simpler: all waves write their kn
    }
    albuf[0][b][kn] = (kn == START_) ? 0.f : NEG_;
    __syncthreads();
    const float* tagb = tag + (size_t)b * T_ * K_ + kn;
    float featc = tagb[0];
    int cur = 0;
    for (int t = 0; t < T_; ++t) {
        float featn = 0.f;
        if (t + 1 < T_) featn = tagb[(size_t)(t + 1) * K_];
        float4 a0 = *(const float4*)&albuf[cur][b][0];
        float4 a1 = *(const float4*)&albuf[cur][b][4];
        float4 a2 = *(const float4*)&albuf[cur][b][8];
        float4 a3 = *(const float4*)&albuf[cur][b][12];
        float v[16];
        v[0] = a0.x + trow[0];  v[1] = a0.y + trow[1];  v[2] = a0.z + trow[2];  v[3] = a0.w + trow[3];
        v[4] = a1.x + trow[4];  v[5] = a1.y + trow[5];  v[6] = a1.z + trow[6];  v[7] = a1.w + trow[7];
        v[8] = a2.x + trow[8];  v[9] = a2.y + trow[9];  v[10] = a2.z + trow[10]; v[11] = a2.w + trow[11];
        v[12] = a3.x + trow[12]; v[13] = a3.y + trow[13]; v[14] = a3.z + trow[14]; v[15] = a3.w + trow[15];
        float m = v[0];
#pragma unroll
        for (int kp = 1; kp < 16; ++kp) m = fmaxf(m, v[kp]);
        float sm = 0.f;
#pragma unroll
        for (int kp = 0; kp < 16; ++kp) sm += __expf(v[kp] - m);
        sm = wave_sum64(sm);                     // DPP: VALU pipe, no LDS
        albuf[cur ^ 1][b][kn] = featc + m + __logf(sm);
        featc = featn;
        __syncthreads();
        cur ^= 1;
    }
    const float term = albuf[cur][b][kn] + trans[STOP_ * 16 + kn];
    albuf[cur ^ 1][b][kn] = term;
    __syncthreads();
    if (tid < 64) {   // all in wave 0
        float mb = -3.4e38f;
#pragma unroll
        for (int k2 = 0; k2 < 16; ++k2) mb = fmaxf(mb, albuf[cur ^ 1][tid][k2]);
        float p = 0.f;
#pragma unroll
        for (int k2 = 0; k2 < 16; ++k2) p += __expf(albuf[cur ^ 1][tid][k2] - mb);
#pragma unroll
        for (int off = 32; off >= 1; off >>= 1) p += __shfl_xor(p, off, 64);
        out[(size_t)B_ * T_ * K_ + tid] = mb + __logf(p);
    }
}

extern "C" void kernel_launch(void* const* d_in, const int* in_sizes, int n_in,
                              void* d_out, int out_size, void* d_ws, size_t ws_size,
                              hipStream_t stream) {
    const int*   x     = (const int*)d_in[0];
    const float* emb   = (const float*)d_in[2];
    const float* w_ih  = (const float*)d_in[3];
    const float* w_hh  = (const float*)d_in[4];
    const float* b_ih  = (const float*)d_in[5];
    const float* b_hh  = (const float*)d_in[6];
    const float* h0    = (const float*)d_in[7];
    const float* c0    = (const float*)d_in[8];
    const float* w_out = (const float*)d_in[9];
    const float* b_out = (const float*)d_in[10];
    const float* trans = (const float*)d_in[11];
    float* out = (float*)d_out;

    // workspace layout (≈199 MB)
    char* ws = (char*)d_ws;
    u32*      wq    = (u32*)ws;                                   // 1 MB   [L][2][1024][64] i8-packed
    float*    dqw   = (float*)(ws + ((size_t)1 << 20));           // 16 KB  [L][2][1024]
    _Float16* wih16 = (_Float16*)(ws + ((size_t)2 << 20));        // 4 MB   [L][2048][512]
    float*    bsum  = (float*)(ws + ((size_t)6 << 20));           // 16 KB  [L][2048]
    _Float16* xe    = (_Float16*)(ws + ((size_t)7 << 20));        // 32 MB  [32768][512] (reused as H1)
    _Float16* Zb    = (_Float16*)(ws + ((size_t)39 << 20));       // 128 MB [32768][2048]
    _Float16* H0b   = (_Float16*)(ws + ((size_t)167 << 20));      // 32 MB  [32768][512]
    if (ws_size < ((size_t)199 << 20)) return;

    quant_whh_k<<<4096, 64, 0, stream>>>(w_hh, wq, dqw);
    cvt_f16_k<<<2048, 256, 0, stream>>>(w_ih, wih16, 2097152 / 4);
    bias_sum_k<<<16, 256, 0, stream>>>(b_ih, b_hh, bsum);
    embed_k<<<B_ * T_, 128, 0, stream>>>(x, emb, xe);

    // layer 0
    gemm_bt<<<(32768 / 128) * (2048 / 128), 256, 0, stream>>>(xe, wih16, bsum, Zb, 32768, 2048, 512);
    lstm_layer_k<<<128, 512, 0, stream>>>(wq, dqw, h0, c0, Zb, H0b);
    // layer 1
    gemm_bt<<<(32768 / 128) * (2048 / 128), 256, 0, stream>>>(H0b, wih16 + (size_t)2048 * 512, bsum + 2048, Zb, 32768, 2048, 512);
    lstm_layer_k<<<128, 512, 0, stream>>>(wq + (size_t)2048 * 64, dqw + 2048,
                                          h0 + 2 * B_ * HD_, c0 + 2 * B_ * HD_, Zb, xe /*H1*/);
    // emissions + CRF
    tag_k<<<32768 / 16, 256, 0, stream>>>(xe, w_out, b_out, out);
    crf_k<<<1, 1024, 0, stream>>>(out, trans, out);
}